// Round 7
// baseline (27.232 us; speedup 1.0000x reference)
//
#include <hip/hip_runtime.h>
#include <math.h>

#define NB 4
#define FRAMES 400
#define NBINS 129
#define HOP 240
#define T_LEN (FRAMES * HOP)   // 96000
#define KLEN 256               // FIR length = 2*(NBINS-1)

#define REC_C { const float cn = fmaf(a2, cm, -cm1); cm1 = cm; cm = cn; }
#define REC_S { const float sn = fmaf(a2, sm, -sm1); sm1 = sm; sm = sn; }

// ---------------------------------------------------------------------------
// Kernel 1 (R5-proven): per (b,frame) windowed minimum-phase FIR, ONE WAVE
// per frame. Thread n in [0,64) computes ker at N = n, n+64, n+128, n+192 via
// the mod-4 phase fold (cos(theta*k*(n+64q)) = cos(theta*k*n + q*k*pi/2)).
// Loop1 coefficients are block-uniform global reads (s_load, zero LDS);
// loops 2/3 read block-computed data as float4 LDS broadcasts (96 b128/wave,
// HALF the per-CU LDS issue of the 128-thread variant since waves halve).
// HW trig in revolutions; Chebyshev recurrences for cos/sin(k*n*2pi/256).
// ---------------------------------------------------------------------------
__global__ __launch_bounds__(64) void gen_fir(const float* __restrict__ log_mag,
                                              float* __restrict__ kern) {
    const int bf = blockIdx.x;   // 0..NB*FRAMES-1
    const int n  = threadIdx.x;  // 0..63

    __shared__ __align__(16) float  g[128];      // Xf[k]/128
    __shared__ __align__(16) float2 crci[128];   // (wC[k], wS[k]); w=1 at k=0 else 2

    const float* lm = log_mag + bf * NBINS;      // block-uniform -> s_load

    const float lmn0 = lm[n];                    // per-lane coalesced
    const float lmn1 = lm[n + 64];

    const float rev_n = (float)n * (1.0f / 256.0f);
    const float ca = __builtin_amdgcn_cosf(rev_n);   // cos(2*pi*n/256)
    const float sa = __builtin_amdgcn_sinf(rev_n);
    const float a2  = 2.0f * ca;
    const float sgn = (n & 1) ? -1.0f : 1.0f;        // (-1)^n ( == (-1)^(n+64q) )

    const float f0s  = lm[0];                    // uniform
    const float f128 = lm[128];

    // ---- Loop 1: Xf[n], Xf[n+64].  U = sum lm[m] cos(theta m n), m=0..127;
    //      V = sum lm[m] cos(theta m (n+64)) via mod-4 phase table.
    {
        float cm1 = ca, cm = 1.0f, sm1 = -sa, sm = 0.0f;
        float U = 0.0f, V = 0.0f;
#pragma unroll
        for (int u = 0; u < 32; ++u) {
            float f;
            f = lm[4 * u + 0]; U = fmaf(f, cm, U); V = fmaf(f, cm, V);  REC_C; REC_S;
            f = lm[4 * u + 1]; U = fmaf(f, cm, U); V = fmaf(-f, sm, V); REC_C; REC_S;
            f = lm[4 * u + 2]; U = fmaf(f, cm, U); V = fmaf(-f, cm, V); REC_C; REC_S;
            f = lm[4 * u + 3]; U = fmaf(f, cm, U); V = fmaf(f, sm, V);  REC_C; REC_S;
        }
        // Xf[N] = -lm[0] + (-1)^n lm[128] + 2*sum_{m=0..127}
        const float base = -f0s + sgn * f128;
        g[n]      = (base + 2.0f * U) * (1.0f / 128.0f);
        g[n + 64] = (base + 2.0f * V) * (1.0f / 128.0f);
    }
    __syncthreads();

    // ---- Loop 2: mp[n] = -sum g[k] sin(theta k n); mp[n+64] via mod-4 table.
    {
        const float4* g4p = (const float4*)g;
        float cm1 = ca, cm = 1.0f, sm1 = -sa, sm = 0.0f;
        float U = 0.0f, V = 0.0f;
#pragma unroll
        for (int u = 0; u < 32; ++u) {
            const float4 gv = g4p[u];
            U = fmaf(gv.x, sm, U); V = fmaf(gv.x, sm, V);  REC_C; REC_S;   // k=4u
            U = fmaf(gv.y, sm, U); V = fmaf(gv.y, cm, V);  REC_C; REC_S;   // k=4u+1
            U = fmaf(gv.z, sm, U); V = fmaf(-gv.z, sm, V); REC_C; REC_S;   // k=4u+2
            U = fmaf(gv.w, sm, U); V = fmaf(-gv.w, cm, V); REC_C; REC_S;   // k=4u+3
        }
        const float mp0 = -U, mp1 = -V;
        const float e0 = __builtin_amdgcn_exp2f(lmn0 * 1.4426950408889634f);
        const float e1 = __builtin_amdgcn_exp2f(lmn1 * 1.4426950408889634f);
        float r0 = mp0 * 0.15915494309189535f; r0 -= floorf(r0);
        float r1 = mp1 * 0.15915494309189535f; r1 -= floorf(r1);
        const float w0 = (n == 0) ? 1.0f : 2.0f;
        crci[n]      = make_float2(w0 * e0 * __builtin_amdgcn_cosf(r0),
                                   w0 * e0 * __builtin_amdgcn_sinf(r0));
        crci[n + 64] = make_float2(2.0f * e1 * __builtin_amdgcn_cosf(r1),
                                   2.0f * e1 * __builtin_amdgcn_sinf(r1));
    }
    __syncthreads();

    // ---- Loop 3: W0..W3, X1, X3 -> four outputs.
    {
        const float4* cc4 = (const float4*)crci;
        float cm1 = ca, cm = 1.0f, sm1 = -sa, sm = 0.0f;
        float W0 = 0.0f, W1 = 0.0f, W2 = 0.0f, W3 = 0.0f, X1 = 0.0f, X3 = 0.0f;
#pragma unroll
        for (int u = 0; u < 32; ++u) {
            const float4 q1 = cc4[2 * u];       // C'[4u], S'[4u], C'[4u+1], S'[4u+1]
            const float4 q2 = cc4[2 * u + 1];   // C'[4u+2], S'[4u+2], C'[4u+3], S'[4u+3]
            W0 = fmaf(q1.x, cm, W0); W0 = fmaf(-q1.y, sm, W0); REC_C; REC_S;   // k=4u
            W1 = fmaf(q1.z, cm, W1); W1 = fmaf(-q1.w, sm, W1);
            X1 = fmaf(q1.z, sm, X1); X1 = fmaf(q1.w, cm, X1);  REC_C; REC_S;   // k=4u+1
            W2 = fmaf(q2.x, cm, W2); W2 = fmaf(-q2.y, sm, W2); REC_C; REC_S;   // k=4u+2
            W3 = fmaf(q2.z, cm, W3); W3 = fmaf(-q2.w, sm, W3);
            X3 = fmaf(q2.z, sm, X3); X3 = fmaf(q2.w, cm, X3);  REC_C; REC_S;   // k=4u+3
        }
        const float e128 = __builtin_amdgcn_exp2f(f128 * 1.4426950408889634f);
        const float base = sgn * e128;
        const float s = 1.0f / 256.0f;
        float* kp = kern + bf * KLEN;
        kp[n]       = (W0 + W1 + W2 + W3 + base) * s;                          // hann=1
        kp[n + 64]  = (W0 - X1 - W2 + X3 + base) * s;                          // hann=1
        kp[n + 128] = (W0 - W1 + W2 - W3 + base) * s * (0.5f + 0.5f * ca);     // tail
        kp[n + 192] = (W0 + X1 - W2 - X3 + base) * s * (0.5f - 0.5f * sa);     // tail
    }
}

// ---------------------------------------------------------------------------
// Kernel 2 (R6-proven): time-varying FIR, frame-segment-aligned blocks.
// Segment bs covers outputs [start,end) that all share (lo,hi):
//   bs=0: [0,120) f=0; bs=1..399: [240bs-120, 240bs+120) f=bs-1;
//   bs=400: [95880,96000) f=399.
// Kernel rows are BLOCK-UNIFORM -> global uniform float4 reads (scalar/L1
// broadcast, zero LDS traffic). LDS holds only the x window; 2 adjacent
// outputs per thread via the b64+carry pattern.
// ---------------------------------------------------------------------------
__global__ __launch_bounds__(128) void fir_apply(const float* __restrict__ ex,
                                                 const float* __restrict__ kern,
                                                 float* __restrict__ out) {
    const int b   = blockIdx.y;
    const int bs  = blockIdx.x;               // 0..400
    const int tid = threadIdx.x;

    const int start = (bs == 0) ? 0 : 240 * bs - 120;
    const int end   = min(T_LEN, 240 * bs + 120);
    const int f     = (bs == 0) ? 0 : bs - 1;
    const int fh    = min(f + 1, FRAMES - 1);

    __shared__ float xs[496];                 // x[start-255 .. start+240]

    const float* xb = ex + b * T_LEN;
    for (int i = tid; i < 496; i += 128) {
        const int t = start - 255 + i;
        xs[i] = (t >= 0 && t < T_LEN) ? xb[t] : 0.0f;
    }
    __syncthreads();

    const int te = start + 2 * tid;
    if (te >= end) return;

    // interpolation weights (lo = f for the whole block by construction)
    float se = ((float)te + 0.5f) * (1.0f / HOP) - 0.5f;
    se = fminf(fmaxf(se, 0.0f), (float)(FRAMES - 1));
    float so = ((float)te + 1.5f) * (1.0f / HOP) - 0.5f;
    so = fminf(fmaxf(so, 0.0f), (float)(FRAMES - 1));
    const float we = se - (float)f;
    const float wo = so - (float)f;

    const float* kL = kern + (b * FRAMES + f)  * KLEN;   // block-uniform rows
    const float* kH = kern + (b * FRAMES + fh) * KLEN;

    // x[te-j] = xs[255 + 2*tid - j]
    const int base = 2 * tid;
    float carry = xs[base + 256];             // x[te+1]
    float aeL = 0.0f, aeH = 0.0f, aoL = 0.0f, aoH = 0.0f;
#pragma unroll 4
    for (int u = 0; u < 64; ++u) {
        const float2 v1 = *(const float2*)&xs[base + 254 - 4 * u];  // x[te-4u-1], x[te-4u]
        const float2 v0 = *(const float2*)&xs[base + 252 - 4 * u];  // x[te-4u-3], x[te-4u-2]
        const float4 kl4 = *(const float4*)(kL + 4 * u);            // uniform
        const float4 kh4 = *(const float4*)(kH + 4 * u);            // uniform
        // tap j=4u   : e->v1.y  o->carry
        aeL = fmaf(v1.y,  kl4.x, aeL); aeH = fmaf(v1.y,  kh4.x, aeH);
        aoL = fmaf(carry, kl4.x, aoL); aoH = fmaf(carry, kh4.x, aoH);
        // tap j=4u+1 : e->v1.x  o->v1.y
        aeL = fmaf(v1.x,  kl4.y, aeL); aeH = fmaf(v1.x,  kh4.y, aeH);
        aoL = fmaf(v1.y,  kl4.y, aoL); aoH = fmaf(v1.y,  kh4.y, aoH);
        // tap j=4u+2 : e->v0.y  o->v1.x
        aeL = fmaf(v0.y,  kl4.z, aeL); aeH = fmaf(v0.y,  kh4.z, aeH);
        aoL = fmaf(v1.x,  kl4.z, aoL); aoH = fmaf(v1.x,  kh4.z, aoH);
        // tap j=4u+3 : e->v0.x  o->v0.y
        aeL = fmaf(v0.x,  kl4.w, aeL); aeH = fmaf(v0.x,  kh4.w, aeH);
        aoL = fmaf(v0.y,  kl4.w, aoL); aoH = fmaf(v0.y,  kh4.w, aoH);
        carry = v0.x;
    }

    const float y0 = aeL + we * (aeH - aeL);
    const float y1 = aoL + wo * (aoH - aoL);
    *(float2*)(out + b * T_LEN + te) = make_float2(y0, y1);  // te even -> aligned
}

// ---------------------------------------------------------------------------
extern "C" void kernel_launch(void* const* d_in, const int* in_sizes, int n_in,
                              void* d_out, int out_size, void* d_ws, size_t ws_size,
                              hipStream_t stream) {
    const float* ex      = (const float*)d_in[0];
    const float* log_mag = (const float*)d_in[1];
    float* kern = (float*)d_ws;          // NB*FRAMES*KLEN floats = 1.6 MB
    float* out  = (float*)d_out;

    gen_fir<<<NB * FRAMES, 64, 0, stream>>>(log_mag, kern);

    dim3 grid(401, NB);                  // 401 frame-aligned segments per batch
    fir_apply<<<grid, 128, 0, stream>>>(ex, kern, out);
}